// Round 3
// baseline (2120.524 us; speedup 1.0000x reference)
//
#include <hip/hip_runtime.h>
#include <hip/hip_bf16.h>
#include <math.h>

#define DIMK 512
#define EPSF 1e-8f
#define LN_EPSF 1e-5f

#define BM 64
#define BN 64
#define BK 32

// ---------------------------------------------------------------------------
// Per-row mean / rstd for layernorm (inputs & context in one launch).
// grid (16384, 2), block 256.  Row length 512: each thread loads 2 elems.
// ---------------------------------------------------------------------------
__global__ __launch_bounds__(256) void ln_stats_kernel(
    const float* __restrict__ X1, const float* __restrict__ X2,
    float2* __restrict__ S1, float2* __restrict__ S2)
{
    const float* X = blockIdx.y ? X2 : X1;
    float2* S = blockIdx.y ? S2 : S1;
    const float* row = X + (size_t)blockIdx.x * DIMK;
    float a = row[threadIdx.x];
    float b = row[threadIdx.x + 256];
    float s = a + b;
    float q = fmaf(a, a, b * b);
#pragma unroll
    for (int off = 32; off > 0; off >>= 1) {
        s += __shfl_down(s, off, 64);
        q += __shfl_down(q, off, 64);
    }
    __shared__ float ls[4], lq[4];
    int lane = threadIdx.x & 63, w = threadIdx.x >> 6;
    if (lane == 0) { ls[w] = s; lq[w] = q; }
    __syncthreads();
    if (threadIdx.x == 0) {
        float st = ls[0] + ls[1] + ls[2] + ls[3];
        float qt = lq[0] + lq[1] + lq[2] + lq[3];
        float mu = st * (1.0f / DIMK);
        float var = qt * (1.0f / DIMK) - mu * mu;
        float2 o;
        o.x = mu;
        o.y = rsqrtf(var + LN_EPSF);
        S[blockIdx.x] = o;
    }
}

// ---------------------------------------------------------------------------
// C[M,512] = LN(A) @ W + bias.  LN applied on the fly while staging A.
// grid (512/BN, M/BM), block 256.  64x64 tile, BK=32, 4x4 per thread.
// ---------------------------------------------------------------------------
__global__ __launch_bounds__(256) void gemm_ln_kernel(
    const float* __restrict__ A, const float2* __restrict__ stats,
    const float* __restrict__ g, const float* __restrict__ bln,
    const float* __restrict__ W, const float* __restrict__ bias,
    float* __restrict__ C)
{
    __shared__ float As[BK][BM + 1];   // k-major, padded: conflict-free
    __shared__ float Bs[BK][BN];
    const int tid = threadIdx.x;
    const int rowBase = blockIdx.y * BM;
    const int colBase = blockIdx.x * BN;
    const int kk = tid & 31, rsub = tid >> 5;   // A-load role
    const int cB = tid & 63, ksub = tid >> 6;   // B-load role
    const int tx = tid & 15, ty = tid >> 4;     // compute role

    float2 st[8];
#pragma unroll
    for (int p = 0; p < 8; ++p) st[p] = stats[rowBase + rsub + p * 8];

    float acc[4][4] = {};
    for (int k0 = 0; k0 < DIMK; k0 += BK) {
        float gk = g[k0 + kk];
        float bk_ = bln[k0 + kk];
#pragma unroll
        for (int p = 0; p < 8; ++p) {
            int r = rsub + p * 8;
            float x = A[(size_t)(rowBase + r) * DIMK + k0 + kk];
            As[kk][r] = (x - st[p].x) * st[p].y * gk + bk_;
        }
#pragma unroll
        for (int p = 0; p < 8; ++p) {
            int kr = ksub + p * 4;
            Bs[kr][cB] = W[(size_t)(k0 + kr) * DIMK + colBase + cB];
        }
        __syncthreads();
#pragma unroll
        for (int kki = 0; kki < BK; ++kki) {
            float av[4], bv[4];
#pragma unroll
            for (int e = 0; e < 4; ++e) av[e] = As[kki][ty * 4 + e];
#pragma unroll
            for (int e = 0; e < 4; ++e) bv[e] = Bs[kki][tx * 4 + e];
#pragma unroll
            for (int i = 0; i < 4; ++i)
#pragma unroll
                for (int j = 0; j < 4; ++j) acc[i][j] = fmaf(av[i], bv[j], acc[i][j]);
        }
        __syncthreads();
    }
#pragma unroll
    for (int i = 0; i < 4; ++i) {
        int r = rowBase + ty * 4 + i;
#pragma unroll
        for (int j = 0; j < 4; ++j) {
            int c = colBase + tx * 4 + j;
            C[(size_t)r * DIMK + c] = acc[i][j] + bias[c];
        }
    }
}

// ---------------------------------------------------------------------------
// dots[b] = scale * q[b] @ k[b]^T.   grid (2048/BN, 2048/BM, 8), block 256.
// ---------------------------------------------------------------------------
__global__ __launch_bounds__(256) void gemm_nt_kernel(
    const float* __restrict__ Q, const float* __restrict__ Kt,
    float* __restrict__ D)
{
    __shared__ float As[BK][BM + 1];
    __shared__ float Bs[BK][BN + 1];
    const size_t bofs = (size_t)blockIdx.z * 2048 * DIMK;
    const float* Ab = Q + bofs;
    const float* Bb = Kt + bofs;
    float* Db = D + (size_t)blockIdx.z * 2048 * 2048;
    const int tid = threadIdx.x;
    const int iBase = blockIdx.y * BM;
    const int jBase = blockIdx.x * BN;
    const int kk = tid & 31, rsub = tid >> 5;
    const int tx = tid & 15, ty = tid >> 4;

    float acc[4][4] = {};
    for (int k0 = 0; k0 < DIMK; k0 += BK) {
#pragma unroll
        for (int p = 0; p < 8; ++p) {
            int r = rsub + p * 8;
            As[kk][r] = Ab[(size_t)(iBase + r) * DIMK + k0 + kk];
            Bs[kk][r] = Bb[(size_t)(jBase + r) * DIMK + k0 + kk];
        }
        __syncthreads();
#pragma unroll
        for (int kki = 0; kki < BK; ++kki) {
            float av[4], bv[4];
#pragma unroll
            for (int e = 0; e < 4; ++e) av[e] = As[kki][ty * 4 + e];
#pragma unroll
            for (int e = 0; e < 4; ++e) bv[e] = Bs[kki][tx * 4 + e];
#pragma unroll
            for (int i = 0; i < 4; ++i)
#pragma unroll
                for (int j = 0; j < 4; ++j) acc[i][j] = fmaf(av[i], bv[j], acc[i][j]);
        }
        __syncthreads();
    }
    const float scale = 0.04419417382415922f;  // 512^-0.5
#pragma unroll
    for (int i = 0; i < 4; ++i) {
        int r = iBase + ty * 4 + i;
#pragma unroll
        for (int j = 0; j < 4; ++j) {
            int c = jBase + tx * 4 + j;
            Db[(size_t)r * 2048 + c] = acc[i][j] * scale;
        }
    }
}

// ---------------------------------------------------------------------------
// Softmax over axis i (queries) for each column j, then + EPS.  In-place.
// grid (2048/64, 8), block 256 laid out as 64 cols x 4 i-groups.
// ---------------------------------------------------------------------------
__global__ __launch_bounds__(256) void col_softmax_kernel(float* __restrict__ D)
{
    const int c = threadIdx.x & 63;
    const int gq = threadIdx.x >> 6;
    const int j = blockIdx.x * 64 + c;
    float* Db = D + (size_t)blockIdx.y * 2048 * 2048;
    __shared__ float red[4][64];
    __shared__ float Mcol[64], Scol[64];

    float m = -INFINITY;
    for (int i = gq; i < 2048; i += 4)
        m = fmaxf(m, Db[(size_t)i * 2048 + j]);
    red[gq][c] = m;
    __syncthreads();
    if (gq == 0)
        Mcol[c] = fmaxf(fmaxf(red[0][c], red[1][c]), fmaxf(red[2][c], red[3][c]));
    __syncthreads();
    const float M = Mcol[c];

    float s = 0.f;
    for (int i = gq; i < 2048; i += 4)
        s += __expf(Db[(size_t)i * 2048 + j] - M);
    red[gq][c] = s;
    __syncthreads();
    if (gq == 0)
        Scol[c] = red[0][c] + red[1][c] + red[2][c] + red[3][c];
    __syncthreads();
    const float inv = 1.0f / Scol[c];

    for (int i = gq; i < 2048; i += 4) {
        size_t idx = (size_t)i * 2048 + j;
        Db[idx] = __expf(Db[idx] - M) * inv + EPSF;
    }
}

// ---------------------------------------------------------------------------
// recip[b,i] = 1 / (sum_j attn[b,i,j] + EPS).  grid 16384, block 256.
// ---------------------------------------------------------------------------
__global__ __launch_bounds__(256) void rowsum_kernel(
    const float* __restrict__ D, float* __restrict__ recip)
{
    const float* row = D + (size_t)blockIdx.x * 2048;
    float s = 0.f;
    for (int t = threadIdx.x; t < 2048; t += 256) s += row[t];
#pragma unroll
    for (int off = 32; off > 0; off >>= 1) s += __shfl_down(s, off, 64);
    __shared__ float ls[4];
    int lane = threadIdx.x & 63, w = threadIdx.x >> 6;
    if (lane == 0) ls[w] = s;
    __syncthreads();
    if (threadIdx.x == 0)
        recip[blockIdx.x] = 1.0f / (ls[0] + ls[1] + ls[2] + ls[3] + EPSF);
}

// ---------------------------------------------------------------------------
// out[b] = diag(recip) * attn[b] @ v[b], fp32 store.
// grid (512/BN, 2048/BM, 8), block 256.
// ---------------------------------------------------------------------------
__global__ __launch_bounds__(256) void gemm_upd_kernel(
    const float* __restrict__ Attn, const float* __restrict__ V,
    const float* __restrict__ recip, float* __restrict__ O)
{
    __shared__ float As[BK][BM + 1];
    __shared__ float Bs[BK][BN];
    const size_t ab = (size_t)blockIdx.z * 2048 * 2048;
    const size_t vb = (size_t)blockIdx.z * 2048 * DIMK;
    const int tid = threadIdx.x;
    const int rowBase = blockIdx.y * BM;
    const int colBase = blockIdx.x * BN;
    const int kk = tid & 31, rsub = tid >> 5;
    const int cB = tid & 63, ksub = tid >> 6;
    const int tx = tid & 15, ty = tid >> 4;

    float acc[4][4] = {};
    for (int k0 = 0; k0 < 2048; k0 += BK) {
#pragma unroll
        for (int p = 0; p < 8; ++p) {
            int r = rsub + p * 8;
            As[kk][r] = Attn[ab + (size_t)(rowBase + r) * 2048 + k0 + kk];
        }
#pragma unroll
        for (int p = 0; p < 8; ++p) {
            int kr = ksub + p * 4;
            Bs[kr][cB] = V[vb + (size_t)(k0 + kr) * DIMK + colBase + cB];
        }
        __syncthreads();
#pragma unroll
        for (int kki = 0; kki < BK; ++kki) {
            float av[4], bv[4];
#pragma unroll
            for (int e = 0; e < 4; ++e) av[e] = As[kki][ty * 4 + e];
#pragma unroll
            for (int e = 0; e < 4; ++e) bv[e] = Bs[kki][tx * 4 + e];
#pragma unroll
            for (int i = 0; i < 4; ++i)
#pragma unroll
                for (int j = 0; j < 4; ++j) acc[i][j] = fmaf(av[i], bv[j], acc[i][j]);
        }
        __syncthreads();
    }
#pragma unroll
    for (int i = 0; i < 4; ++i) {
        int r = rowBase + ty * 4 + i;
        float rs = recip[blockIdx.z * 2048 + r];
#pragma unroll
        for (int j = 0; j < 4; ++j) {
            int c = colBase + tx * 4 + j;
            O[((size_t)blockIdx.z * 2048 + r) * DIMK + c] = acc[i][j] * rs;
        }
    }
}

// ---------------------------------------------------------------------------
extern "C" void kernel_launch(void* const* d_in, const int* in_sizes, int n_in,
                              void* d_out, int out_size, void* d_ws, size_t ws_size,
                              hipStream_t stream)
{
    const float* inputs  = (const float*)d_in[0];   // [8,2048,512]
    const float* context = (const float*)d_in[1];   // [8,2048,512]
    const float* g_in    = (const float*)d_in[2];
    const float* b_in    = (const float*)d_in[3];
    const float* g_ctx   = (const float*)d_in[4];
    const float* b_ctx   = (const float*)d_in[5];
    const float* Wq      = (const float*)d_in[6];
    const float* bq      = (const float*)d_in[7];
    const float* Wk      = (const float*)d_in[8];
    const float* bk      = (const float*)d_in[9];
    const float* Wv      = (const float*)d_in[10];
    const float* bv      = (const float*)d_in[11];
    float* out = (float*)d_out;                     // [8,2048,512] fp32

    // workspace layout (floats)
    const size_t ROWS = 8ull * 2048;                 // 16384
    const size_t QKV  = ROWS * DIMK;                 // 8388608
    const size_t DOTS = 8ull * 2048 * 2048;          // 33554432
    float* ws = (float*)d_ws;
    float2* stats_in  = (float2*)ws;                 // 16384 float2
    float2* stats_ctx = stats_in + ROWS;             // 16384 float2
    float* q     = ws + 4 * ROWS;
    float* k     = q + QKV;
    float* v     = k + QKV;
    float* recip = v + QKV;
    float* dots  = recip + ROWS;
    size_t need_bytes = (4 * ROWS + 3 * QKV + ROWS + DOTS) * sizeof(float);
    if (ws_size < need_bytes) return;  // fail loudly via validation mismatch

    ln_stats_kernel<<<dim3(ROWS, 2), 256, 0, stream>>>(inputs, context, stats_in, stats_ctx);

    gemm_ln_kernel<<<dim3(8, 256), 256, 0, stream>>>(inputs,  stats_in,  g_in,  b_in,  Wq, bq, q);
    gemm_ln_kernel<<<dim3(8, 256), 256, 0, stream>>>(context, stats_ctx, g_ctx, b_ctx, Wk, bk, k);
    gemm_ln_kernel<<<dim3(8, 256), 256, 0, stream>>>(context, stats_ctx, g_ctx, b_ctx, Wv, bv, v);

    gemm_nt_kernel<<<dim3(32, 32, 8), 256, 0, stream>>>(q, k, dots);

    col_softmax_kernel<<<dim3(32, 8), 256, 0, stream>>>(dots);
    rowsum_kernel<<<16384, 256, 0, stream>>>(dots, recip);

    gemm_upd_kernel<<<dim3(8, 32, 8), 256, 0, stream>>>(dots, v, recip, out);
}

// Round 4
// 653.219 us; speedup vs baseline: 3.2463x; 3.2463x over previous
//
#include <hip/hip_runtime.h>
#include <hip/hip_bf16.h>
#include <math.h>

#define EPSF 1e-8f
#define LN_EPSF 1e-5f
#define SCALE_QK 0.04419417382415922f   // 512^-0.5

typedef unsigned short ushort_t;
typedef __bf16 bhalf;
typedef bhalf bhalf8 __attribute__((ext_vector_type(8)));
typedef float f32x4 __attribute__((ext_vector_type(4)));

__device__ __forceinline__ float b2f(ushort_t u) {
    return __uint_as_float((unsigned)u << 16);
}
// fp32 -> bf16 RNE (matches numpy/jax rounding)
__device__ __forceinline__ ushort_t f2b(float f) {
    unsigned x = __float_as_uint(f);
    return (ushort_t)((x + 0x7fffu + ((x >> 16) & 1u)) >> 16);
}

// ---------------------------------------------------------------------------
// LayerNorm: stats + apply + bf16 store in one pass.
// grid (16384, 2), block 256.  Row = 512 floats, 2 per thread.
// ---------------------------------------------------------------------------
__global__ __launch_bounds__(256) void ln_apply_kernel(
    const float* __restrict__ X1, const float* __restrict__ X2,
    const float* __restrict__ g1, const float* __restrict__ b1,
    const float* __restrict__ g2, const float* __restrict__ b2,
    ushort_t* __restrict__ O1, ushort_t* __restrict__ O2)
{
    const bool sec = blockIdx.y != 0;
    const float* X = sec ? X2 : X1;
    const float* g = sec ? g2 : g1;
    const float* b = sec ? b2 : b1;
    ushort_t* O = sec ? O2 : O1;
    const size_t base = (size_t)blockIdx.x * 512;
    const int t = threadIdx.x;
    float a = X[base + t];
    float c = X[base + t + 256];
    float s = a + c;
    float q = fmaf(a, a, c * c);
#pragma unroll
    for (int off = 32; off > 0; off >>= 1) {
        s += __shfl_down(s, off, 64);
        q += __shfl_down(q, off, 64);
    }
    __shared__ float ls[4], lq[4], mv[2];
    int lane = t & 63, w = t >> 6;
    if (lane == 0) { ls[w] = s; lq[w] = q; }
    __syncthreads();
    if (t == 0) {
        float st = ls[0] + ls[1] + ls[2] + ls[3];
        float qt = lq[0] + lq[1] + lq[2] + lq[3];
        float mu = st * (1.0f / 512.0f);
        float var = qt * (1.0f / 512.0f) - mu * mu;
        mv[0] = mu;
        mv[1] = rsqrtf(var + LN_EPSF);
    }
    __syncthreads();
    float mu = mv[0], rstd = mv[1];
    O[base + t]       = f2b((a - mu) * rstd * g[t] + b[t]);
    O[base + t + 256] = f2b((c - mu) * rstd * g[t + 256] + b[t + 256]);
}

// ---------------------------------------------------------------------------
// Transpose 512x512 fp32 weight -> bf16 [n][k].  grid (16,16,3), block 256.
// ---------------------------------------------------------------------------
__global__ __launch_bounds__(256) void wtrans_kernel(
    const float* __restrict__ W0, const float* __restrict__ W1,
    const float* __restrict__ W2,
    ushort_t* __restrict__ T0, ushort_t* __restrict__ T1,
    ushort_t* __restrict__ T2)
{
    const float* W = blockIdx.z == 0 ? W0 : (blockIdx.z == 1 ? W1 : W2);
    ushort_t* T = blockIdx.z == 0 ? T0 : (blockIdx.z == 1 ? T1 : T2);
    __shared__ float tile[32][33];
    int tx = threadIdx.x & 31, ty = threadIdx.x >> 5;
    int r0 = blockIdx.y * 32, c0 = blockIdx.x * 32;
#pragma unroll
    for (int p = 0; p < 4; ++p)
        tile[ty + p * 8][tx] = W[(size_t)(r0 + ty + p * 8) * 512 + c0 + tx];
    __syncthreads();
#pragma unroll
    for (int p = 0; p < 4; ++p)
        T[(size_t)(c0 + ty + p * 8) * 512 + r0 + tx] = f2b(tile[tx][ty + p * 8]);
}

// ---------------------------------------------------------------------------
// Transpose v (bf16) [b][2048][512] -> vT [b][512][2048].  grid (16,64,8).
// ---------------------------------------------------------------------------
__global__ __launch_bounds__(256) void vtrans_kernel(
    const ushort_t* __restrict__ V, ushort_t* __restrict__ VT)
{
    __shared__ ushort_t tile[32][33];
    const size_t vb = (size_t)blockIdx.z * 2048 * 512;
    const size_t tb = (size_t)blockIdx.z * 512 * 2048;
    int tx = threadIdx.x & 31, ty = threadIdx.x >> 5;
    int j0 = blockIdx.y * 32, d0 = blockIdx.x * 32;
#pragma unroll
    for (int p = 0; p < 4; ++p)
        tile[ty + p * 8][tx] = V[vb + (size_t)(j0 + ty + p * 8) * 512 + d0 + tx];
    __syncthreads();
#pragma unroll
    for (int p = 0; p < 4; ++p)
        VT[tb + (size_t)(d0 + ty + p * 8) * 2048 + j0 + tx] = tile[tx][ty + p * 8];
}

// ---------------------------------------------------------------------------
// NT bf16 MFMA GEMM: C[M,N] = sum_k A[m][k]*B[n][k], both k-major bf16.
// 128x128 tile, 4 waves, each 64x64 = 4x4 MFMA 16x16x32 tiles, BK=32.
// MODE 0: +bias (aux[col]),  bf16 store       (q/k/v projections)
// MODE 1: *scale,            bf16 store       (dots)
// MODE 2: *aux[row] (recip), fp32 store       (updates)
// ---------------------------------------------------------------------------
template <int MODE>
__global__ __launch_bounds__(256) void mfma_gemm_kernel(
    const ushort_t* __restrict__ A, const ushort_t* __restrict__ B,
    void* __restrict__ Cout, const float* __restrict__ aux,
    int K, int N, size_t strideA, size_t strideB, size_t strideC,
    int auxStride, float scale)
{
    __shared__ ushort_t As[128][40];   // 80B row stride: <=2-way bank alias
    __shared__ ushort_t Bs[128][40];
    const int tid = threadIdx.x;
    const ushort_t* Ab = A + strideA * blockIdx.z;
    const ushort_t* Bb = B + strideB * blockIdx.z;
    const int m0 = blockIdx.y * 128;
    const int n0 = blockIdx.x * 128;
    const int sr = tid >> 2;           // staging row 0..63 (+64)
    const int sc = (tid & 3) * 8;      // staging k-offset
    const int wave = tid >> 6;
    const int lane = tid & 63;
    const int fm = lane & 15;
    const int fq = lane >> 4;
    const int wm = (wave >> 1) * 64;
    const int wn = (wave & 1) * 64;

    f32x4 acc[4][4];
#pragma unroll
    for (int i = 0; i < 4; ++i)
#pragma unroll
        for (int j = 0; j < 4; ++j) acc[i][j] = (f32x4){0.f, 0.f, 0.f, 0.f};

    const ushort_t* Arow0 = Ab + (size_t)(m0 + sr) * K + sc;
    const ushort_t* Arow1 = Ab + (size_t)(m0 + sr + 64) * K + sc;
    const ushort_t* Brow0 = Bb + (size_t)(n0 + sr) * K + sc;
    const ushort_t* Brow1 = Bb + (size_t)(n0 + sr + 64) * K + sc;

    for (int k0 = 0; k0 < K; k0 += 32) {
        uint4 a0 = *(const uint4*)(Arow0 + k0);
        uint4 a1 = *(const uint4*)(Arow1 + k0);
        uint4 b0 = *(const uint4*)(Brow0 + k0);
        uint4 b1 = *(const uint4*)(Brow1 + k0);
        __syncthreads();
        *(uint4*)&As[sr][sc] = a0;
        *(uint4*)&As[sr + 64][sc] = a1;
        *(uint4*)&Bs[sr][sc] = b0;
        *(uint4*)&Bs[sr + 64][sc] = b1;
        __syncthreads();
        bhalf8 af[4], bfr[4];
#pragma unroll
        for (int t = 0; t < 4; ++t) {
            af[t]  = *(const bhalf8*)&As[wm + t * 16 + fm][fq * 8];
            bfr[t] = *(const bhalf8*)&Bs[wn + t * 16 + fm][fq * 8];
        }
#pragma unroll
        for (int i = 0; i < 4; ++i)
#pragma unroll
            for (int j = 0; j < 4; ++j)
                acc[i][j] = __builtin_amdgcn_mfma_f32_16x16x32_bf16(
                    af[i], bfr[j], acc[i][j], 0, 0, 0);
    }

    if (MODE == 2) {
        float* C = (float*)Cout + strideC * blockIdx.z;
        const float* rc = aux + (size_t)auxStride * blockIdx.z;
#pragma unroll
        for (int ti = 0; ti < 4; ++ti) {
#pragma unroll
            for (int r = 0; r < 4; ++r) {
                int row = m0 + wm + ti * 16 + fq * 4 + r;
                float rs = rc[row];
#pragma unroll
                for (int tj = 0; tj < 4; ++tj) {
                    int col = n0 + wn + tj * 16 + fm;
                    C[(size_t)row * N + col] = acc[ti][tj][r] * rs;
                }
            }
        }
    } else {
        ushort_t* C = (ushort_t*)Cout + strideC * blockIdx.z;
#pragma unroll
        for (int ti = 0; ti < 4; ++ti) {
#pragma unroll
            for (int r = 0; r < 4; ++r) {
                int row = m0 + wm + ti * 16 + fq * 4 + r;
#pragma unroll
                for (int tj = 0; tj < 4; ++tj) {
                    int col = n0 + wn + tj * 16 + fm;
                    float v = acc[ti][tj][r];
                    v = (MODE == 0) ? v + aux[col] : v * scale;
                    C[(size_t)row * N + col] = f2b(v);
                }
            }
        }
    }
}

// ---------------------------------------------------------------------------
// Column softmax (over i) on bf16 dots, in place, + EPS.  2 memory passes
// (online max+sum, then write).  grid (32, 8), block 256 = 64 cols x 4 grp.
// ---------------------------------------------------------------------------
__global__ __launch_bounds__(256) void col_softmax_kernel(ushort_t* __restrict__ D)
{
    const int c = threadIdx.x & 63;
    const int gq = threadIdx.x >> 6;
    const int j = blockIdx.x * 64 + c;
    ushort_t* Db = D + (size_t)blockIdx.y * 2048 * 2048;
    __shared__ float redm[4][64], reds[4][64];
    __shared__ float Mcol[64], Icol[64];

    float m = -1e30f, s = 0.f;
    for (int i = gq; i < 2048; i += 4) {
        float x = b2f(Db[(size_t)i * 2048 + j]);
        if (x > m) { s = s * __expf(m - x) + 1.0f; m = x; }
        else        s += __expf(x - m);
    }
    redm[gq][c] = m;
    reds[gq][c] = s;
    __syncthreads();
    if (gq == 0) {
        float M = fmaxf(fmaxf(redm[0][c], redm[1][c]), fmaxf(redm[2][c], redm[3][c]));
        float S = reds[0][c] * __expf(redm[0][c] - M)
                + reds[1][c] * __expf(redm[1][c] - M)
                + reds[2][c] * __expf(redm[2][c] - M)
                + reds[3][c] * __expf(redm[3][c] - M);
        Mcol[c] = M;
        Icol[c] = 1.0f / S;
    }
    __syncthreads();
    const float M = Mcol[c], inv = Icol[c];
    for (int i = gq; i < 2048; i += 4) {
        size_t idx = (size_t)i * 2048 + j;
        float x = b2f(Db[idx]);
        Db[idx] = f2b(__expf(x - M) * inv + EPSF);
    }
}

// ---------------------------------------------------------------------------
// recip[row] = 1/(sum_j attn[row,j] + EPS), attn bf16.  grid 16384, block 256.
// ---------------------------------------------------------------------------
__global__ __launch_bounds__(256) void rowsum_kernel(
    const ushort_t* __restrict__ Attn, float* __restrict__ recip)
{
    const uint4* rp = (const uint4*)(Attn + (size_t)blockIdx.x * 2048);
    uint4 u = rp[threadIdx.x];
    unsigned w0 = u.x, w1 = u.y, w2 = u.z, w3 = u.w;
    float s = __uint_as_float(w0 << 16) + __uint_as_float(w0 & 0xffff0000u)
            + __uint_as_float(w1 << 16) + __uint_as_float(w1 & 0xffff0000u)
            + __uint_as_float(w2 << 16) + __uint_as_float(w2 & 0xffff0000u)
            + __uint_as_float(w3 << 16) + __uint_as_float(w3 & 0xffff0000u);
#pragma unroll
    for (int off = 32; off > 0; off >>= 1) s += __shfl_down(s, off, 64);
    __shared__ float ls[4];
    int lane = threadIdx.x & 63, wv = threadIdx.x >> 6;
    if (lane == 0) ls[wv] = s;
    __syncthreads();
    if (threadIdx.x == 0)
        recip[blockIdx.x] = 1.0f / (ls[0] + ls[1] + ls[2] + ls[3] + EPSF);
}

// ---------------------------------------------------------------------------
extern "C" void kernel_launch(void* const* d_in, const int* in_sizes, int n_in,
                              void* d_out, int out_size, void* d_ws, size_t ws_size,
                              hipStream_t stream)
{
    const float* inputs  = (const float*)d_in[0];
    const float* context = (const float*)d_in[1];
    const float* g_in    = (const float*)d_in[2];
    const float* b_in    = (const float*)d_in[3];
    const float* g_ctx   = (const float*)d_in[4];
    const float* b_ctx   = (const float*)d_in[5];
    const float* Wq      = (const float*)d_in[6];
    const float* bq      = (const float*)d_in[7];
    const float* Wk      = (const float*)d_in[8];
    const float* bk      = (const float*)d_in[9];
    const float* Wv      = (const float*)d_in[10];
    const float* bv      = (const float*)d_in[11];
    float* out = (float*)d_out;                      // [8,2048,512] fp32

    const size_t QKV  = 8ull * 2048 * 512;           // 8,388,608
    const size_t WSZ  = 512ull * 512;                // 262,144
    const size_t DOTS = 8ull * 2048 * 2048;          // 33,554,432

    ushort_t* xln  = (ushort_t*)d_ws;
    ushort_t* cln  = xln + QKV;
    ushort_t* WqT  = cln + QKV;
    ushort_t* WkT  = WqT + WSZ;
    ushort_t* WvT  = WkT + WSZ;
    ushort_t* q    = WvT + WSZ;
    ushort_t* kk   = q + QKV;
    ushort_t* v    = kk + QKV;
    ushort_t* vT   = v + QKV;
    ushort_t* dots = vT + QKV;
    float* recip   = (float*)(dots + DOTS);
    size_t need_bytes = (6 * QKV + 3 * WSZ + DOTS) * 2 + 16384 * 4;
    if (ws_size < need_bytes) return;  // fail loudly via validation mismatch

    ln_apply_kernel<<<dim3(16384, 2), 256, 0, stream>>>(
        inputs, context, g_in, b_in, g_ctx, b_ctx, xln, cln);

    wtrans_kernel<<<dim3(16, 16, 3), 256, 0, stream>>>(Wq, Wk, Wv, WqT, WkT, WvT);

    mfma_gemm_kernel<0><<<dim3(4, 128, 1), 256, 0, stream>>>(
        xln, WqT, q, bq, 512, 512, 0, 0, 0, 0, 1.f);
    mfma_gemm_kernel<0><<<dim3(4, 128, 1), 256, 0, stream>>>(
        cln, WkT, kk, bk, 512, 512, 0, 0, 0, 0, 1.f);
    mfma_gemm_kernel<0><<<dim3(4, 128, 1), 256, 0, stream>>>(
        cln, WvT, v, bv, 512, 512, 0, 0, 0, 0, 1.f);

    vtrans_kernel<<<dim3(16, 64, 8), 256, 0, stream>>>(v, vT);

    mfma_gemm_kernel<1><<<dim3(16, 16, 8), 256, 0, stream>>>(
        q, kk, dots, nullptr, 512, 2048,
        (size_t)2048 * 512, (size_t)2048 * 512, (size_t)2048 * 2048, 0, SCALE_QK);

    col_softmax_kernel<<<dim3(32, 8), 256, 0, stream>>>(dots);
    rowsum_kernel<<<16384, 256, 0, stream>>>(dots, recip);

    mfma_gemm_kernel<2><<<dim3(4, 16, 8), 256, 0, stream>>>(
        dots, vT, out, recip, 2048, 512,
        (size_t)2048 * 2048, (size_t)512 * 2048, (size_t)2048 * 512, 2048, 1.f);
}

// Round 5
// 367.843 us; speedup vs baseline: 5.7647x; 1.7758x over previous
//
#include <hip/hip_runtime.h>
#include <hip/hip_bf16.h>
#include <math.h>

#define EPSF 1e-8f
#define LN_EPSF 1e-5f
#define SCALE_QK 0.04419417382415922f   // 512^-0.5

typedef unsigned short ushort_t;
typedef __bf16 bhalf;
typedef bhalf bhalf8 __attribute__((ext_vector_type(8)));
typedef float f32x4 __attribute__((ext_vector_type(4)));

__device__ __forceinline__ float b2f(ushort_t u) {
    return __uint_as_float((unsigned)u << 16);
}
// fp32 -> bf16 RNE (matches numpy/jax rounding)
__device__ __forceinline__ ushort_t f2b(float f) {
    unsigned x = __float_as_uint(f);
    return (ushort_t)((x + 0x7fffu + ((x >> 16) & 1u)) >> 16);
}
// multiply packed pair of bf16 by two f32 scales, repack
__device__ __forceinline__ unsigned mulpack2(unsigned u, float ca, float cb) {
    float lo = b2f((ushort_t)(u & 0xffffu)) * ca;
    float hi = b2f((ushort_t)(u >> 16)) * cb;
    return (unsigned)f2b(lo) | ((unsigned)f2b(hi) << 16);
}
__device__ __forceinline__ uint4 scale8(uint4 a, float4 c0, float4 c1) {
    a.x = mulpack2(a.x, c0.x, c0.y);
    a.y = mulpack2(a.y, c0.z, c0.w);
    a.z = mulpack2(a.z, c1.x, c1.y);
    a.w = mulpack2(a.w, c1.z, c1.w);
    return a;
}

// ---------------------------------------------------------------------------
// LayerNorm: stats + apply + bf16 store in one pass.
// grid (16384, 2), block 256.  Row = 512 floats, 2 per thread.
// ---------------------------------------------------------------------------
__global__ __launch_bounds__(256) void ln_apply_kernel(
    const float* __restrict__ X1, const float* __restrict__ X2,
    const float* __restrict__ g1, const float* __restrict__ b1,
    const float* __restrict__ g2, const float* __restrict__ b2,
    ushort_t* __restrict__ O1, ushort_t* __restrict__ O2)
{
    const bool sec = blockIdx.y != 0;
    const float* X = sec ? X2 : X1;
    const float* g = sec ? g2 : g1;
    const float* b = sec ? b2 : b1;
    ushort_t* O = sec ? O2 : O1;
    const size_t base = (size_t)blockIdx.x * 512;
    const int t = threadIdx.x;
    float a = X[base + t];
    float c = X[base + t + 256];
    float s = a + c;
    float q = fmaf(a, a, c * c);
#pragma unroll
    for (int off = 32; off > 0; off >>= 1) {
        s += __shfl_down(s, off, 64);
        q += __shfl_down(q, off, 64);
    }
    __shared__ float ls[4], lq[4], mv[2];
    int lane = t & 63, w = t >> 6;
    if (lane == 0) { ls[w] = s; lq[w] = q; }
    __syncthreads();
    if (t == 0) {
        float st = ls[0] + ls[1] + ls[2] + ls[3];
        float qt = lq[0] + lq[1] + lq[2] + lq[3];
        float mu = st * (1.0f / 512.0f);
        float var = qt * (1.0f / 512.0f) - mu * mu;
        mv[0] = mu;
        mv[1] = rsqrtf(var + LN_EPSF);
    }
    __syncthreads();
    float mu = mv[0], rstd = mv[1];
    O[base + t]       = f2b((a - mu) * rstd * g[t] + b[t]);
    O[base + t + 256] = f2b((c - mu) * rstd * g[t + 256] + b[t + 256]);
}

// ---------------------------------------------------------------------------
// Transpose 512x512 fp32 weight -> bf16 [n][k].  grid (16,16,3), block 256.
// ---------------------------------------------------------------------------
__global__ __launch_bounds__(256) void wtrans_kernel(
    const float* __restrict__ W0, const float* __restrict__ W1,
    const float* __restrict__ W2,
    ushort_t* __restrict__ T0, ushort_t* __restrict__ T1,
    ushort_t* __restrict__ T2)
{
    const float* W = blockIdx.z == 0 ? W0 : (blockIdx.z == 1 ? W1 : W2);
    ushort_t* T = blockIdx.z == 0 ? T0 : (blockIdx.z == 1 ? T1 : T2);
    __shared__ float tile[32][33];
    int tx = threadIdx.x & 31, ty = threadIdx.x >> 5;
    int r0 = blockIdx.y * 32, c0 = blockIdx.x * 32;
#pragma unroll
    for (int p = 0; p < 4; ++p)
        tile[ty + p * 8][tx] = W[(size_t)(r0 + ty + p * 8) * 512 + c0 + tx];
    __syncthreads();
#pragma unroll
    for (int p = 0; p < 4; ++p)
        T[(size_t)(c0 + ty + p * 8) * 512 + r0 + tx] = f2b(tile[tx][ty + p * 8]);
}

// ---------------------------------------------------------------------------
// Transpose v (bf16) [b][2048][512] -> vT [b][512][2048].  grid (16,64,8).
// ---------------------------------------------------------------------------
__global__ __launch_bounds__(256) void vtrans_kernel(
    const ushort_t* __restrict__ V, ushort_t* __restrict__ VT)
{
    __shared__ ushort_t tile[32][33];
    const size_t vb = (size_t)blockIdx.z * 2048 * 512;
    const size_t tb = (size_t)blockIdx.z * 512 * 2048;
    int tx = threadIdx.x & 31, ty = threadIdx.x >> 5;
    int j0 = blockIdx.y * 32, d0 = blockIdx.x * 32;
#pragma unroll
    for (int p = 0; p < 4; ++p)
        tile[ty + p * 8][tx] = V[vb + (size_t)(j0 + ty + p * 8) * 512 + d0 + tx];
    __syncthreads();
#pragma unroll
    for (int p = 0; p < 4; ++p)
        VT[tb + (size_t)(d0 + ty + p * 8) * 2048 + j0 + tx] = tile[tx][ty + p * 8];
}

// ---------------------------------------------------------------------------
// NT bf16 MFMA GEMM: C[M,N] = sum_k A[m][k]*B[n][k], both k-major bf16.
// 128x128 tile, 4 waves, each 64x64 = 4x4 MFMA 16x16x32 tiles, BK=32.
// MODE 0: +bias (aux[col]),              bf16 store   (q/k/v projections)
// MODE 1: exp(acc*scale), bf16 store, column-sum partials -> atomic colsum
// MODE 2: A scaled by colrecip[k] at staging; *aux[row] (recip); fp32 store
// ---------------------------------------------------------------------------
template <int MODE>
__global__ __launch_bounds__(256) void mfma_gemm_kernel(
    const ushort_t* __restrict__ A, const ushort_t* __restrict__ B,
    void* __restrict__ Cout, const float* __restrict__ aux,
    float* __restrict__ colsum, const float* __restrict__ colrecip,
    int K, int N, size_t strideA, size_t strideB, size_t strideC,
    int auxStride, float scale)
{
    __shared__ ushort_t As[128][40];   // 80B row stride: <=2-way bank alias
    __shared__ ushort_t Bs[128][40];
    const int tid = threadIdx.x;
    const ushort_t* Ab = A + strideA * blockIdx.z;
    const ushort_t* Bb = B + strideB * blockIdx.z;
    const int m0 = blockIdx.y * 128;
    const int n0 = blockIdx.x * 128;
    const int sr = tid >> 2;           // staging row 0..63 (+64)
    const int sc = (tid & 3) * 8;      // staging k-offset
    const int wave = tid >> 6;
    const int lane = tid & 63;
    const int fm = lane & 15;
    const int fq = lane >> 4;
    const int wm = (wave >> 1) * 64;
    const int wn = (wave & 1) * 64;

    f32x4 acc[4][4];
#pragma unroll
    for (int i = 0; i < 4; ++i)
#pragma unroll
        for (int j = 0; j < 4; ++j) acc[i][j] = (f32x4){0.f, 0.f, 0.f, 0.f};

    const ushort_t* Arow0 = Ab + (size_t)(m0 + sr) * K + sc;
    const ushort_t* Arow1 = Ab + (size_t)(m0 + sr + 64) * K + sc;
    const ushort_t* Brow0 = Bb + (size_t)(n0 + sr) * K + sc;
    const ushort_t* Brow1 = Bb + (size_t)(n0 + sr + 64) * K + sc;

    for (int k0 = 0; k0 < K; k0 += 32) {
        uint4 a0 = *(const uint4*)(Arow0 + k0);
        uint4 a1 = *(const uint4*)(Arow1 + k0);
        uint4 b0 = *(const uint4*)(Brow0 + k0);
        uint4 b1 = *(const uint4*)(Brow1 + k0);
        if (MODE == 2) {
            // A = edots; apply attn = edots * colrecip[j] on the fly
            const float* cr = colrecip + 2048 * blockIdx.z + k0 + sc;
            float4 c0 = *(const float4*)cr;
            float4 c1 = *(const float4*)(cr + 4);
            a0 = scale8(a0, c0, c1);
            a1 = scale8(a1, c0, c1);
        }
        __syncthreads();
        *(uint4*)&As[sr][sc] = a0;
        *(uint4*)&As[sr + 64][sc] = a1;
        *(uint4*)&Bs[sr][sc] = b0;
        *(uint4*)&Bs[sr + 64][sc] = b1;
        __syncthreads();
        bhalf8 af[4], bfr[4];
#pragma unroll
        for (int t = 0; t < 4; ++t) {
            af[t]  = *(const bhalf8*)&As[wm + t * 16 + fm][fq * 8];
            bfr[t] = *(const bhalf8*)&Bs[wn + t * 16 + fm][fq * 8];
        }
#pragma unroll
        for (int i = 0; i < 4; ++i)
#pragma unroll
            for (int j = 0; j < 4; ++j)
                acc[i][j] = __builtin_amdgcn_mfma_f32_16x16x32_bf16(
                    af[i], bfr[j], acc[i][j], 0, 0, 0);
    }

    if (MODE == 2) {
        float* C = (float*)Cout + strideC * blockIdx.z;
        const float* rc = aux + (size_t)auxStride * blockIdx.z;
#pragma unroll
        for (int ti = 0; ti < 4; ++ti) {
#pragma unroll
            for (int r = 0; r < 4; ++r) {
                int row = m0 + wm + ti * 16 + fq * 4 + r;
                float rs = rc[row];
#pragma unroll
                for (int tj = 0; tj < 4; ++tj) {
                    int col = n0 + wn + tj * 16 + fm;
                    C[(size_t)row * N + col] = acc[ti][tj][r] * rs;
                }
            }
        }
    } else if (MODE == 1) {
        ushort_t* C = (ushort_t*)Cout + strideC * blockIdx.z;
        float* colpart = (float*)&As[0][0];
        __syncthreads();               // all fragment reads of As are done
        if (tid < 128) colpart[tid] = 0.f;
        __syncthreads();
        float psum[4] = {0.f, 0.f, 0.f, 0.f};
#pragma unroll
        for (int ti = 0; ti < 4; ++ti) {
#pragma unroll
            for (int r = 0; r < 4; ++r) {
                int row = m0 + wm + ti * 16 + fq * 4 + r;
#pragma unroll
                for (int tj = 0; tj < 4; ++tj) {
                    int col = n0 + wn + tj * 16 + fm;
                    float e = __expf(acc[ti][tj][r] * scale);
                    ushort_t h = f2b(e);
                    C[(size_t)row * N + col] = h;
                    psum[tj] += b2f(h);   // sum the quantized values
                }
            }
        }
#pragma unroll
        for (int tj = 0; tj < 4; ++tj)
            atomicAdd(&colpart[wn + tj * 16 + fm], psum[tj]);
        __syncthreads();
        if (tid < 128)
            atomicAdd(&colsum[2048 * blockIdx.z + n0 + tid], colpart[tid]);
    } else {
        ushort_t* C = (ushort_t*)Cout + strideC * blockIdx.z;
#pragma unroll
        for (int ti = 0; ti < 4; ++ti) {
#pragma unroll
            for (int r = 0; r < 4; ++r) {
                int row = m0 + wm + ti * 16 + fq * 4 + r;
#pragma unroll
                for (int tj = 0; tj < 4; ++tj) {
                    int col = n0 + wn + tj * 16 + fm;
                    C[(size_t)row * N + col] = f2b(acc[ti][tj][r] + aux[col]);
                }
            }
        }
    }
}

// ---------------------------------------------------------------------------
// colrecip[t] = 1/colsum[t].  16384 elems, grid 64, block 256.
// ---------------------------------------------------------------------------
__global__ __launch_bounds__(256) void colrecip_kernel(
    const float* __restrict__ cs, float* __restrict__ cr)
{
    int t = blockIdx.x * 256 + threadIdx.x;
    cr[t] = 1.0f / cs[t];
}

// ---------------------------------------------------------------------------
// recip[i] = 1/(sum_j edots[i,j]*colrecip[j] + 2049*EPS).  grid 16384.
// ---------------------------------------------------------------------------
__global__ __launch_bounds__(256) void rowsum_kernel(
    const ushort_t* __restrict__ E, const float* __restrict__ colrecip,
    float* __restrict__ recip)
{
    const uint4* rp = (const uint4*)(E + (size_t)blockIdx.x * 2048);
    const float4* cr = (const float4*)(colrecip + (blockIdx.x >> 11) * 2048);
    uint4 u = rp[threadIdx.x];
    float4 c0 = cr[threadIdx.x * 2];
    float4 c1 = cr[threadIdx.x * 2 + 1];
    float s = b2f((ushort_t)(u.x & 0xffffu)) * c0.x
            + b2f((ushort_t)(u.x >> 16))    * c0.y
            + b2f((ushort_t)(u.y & 0xffffu)) * c0.z
            + b2f((ushort_t)(u.y >> 16))    * c0.w
            + b2f((ushort_t)(u.z & 0xffffu)) * c1.x
            + b2f((ushort_t)(u.z >> 16))    * c1.y
            + b2f((ushort_t)(u.w & 0xffffu)) * c1.z
            + b2f((ushort_t)(u.w >> 16))    * c1.w;
#pragma unroll
    for (int off = 32; off > 0; off >>= 1) s += __shfl_down(s, off, 64);
    __shared__ float ls[4];
    int lane = threadIdx.x & 63, wv = threadIdx.x >> 6;
    if (lane == 0) ls[wv] = s;
    __syncthreads();
    if (threadIdx.x == 0)
        recip[blockIdx.x] = 1.0f / (ls[0] + ls[1] + ls[2] + ls[3] + 2.049e-5f);
}

// ---------------------------------------------------------------------------
extern "C" void kernel_launch(void* const* d_in, const int* in_sizes, int n_in,
                              void* d_out, int out_size, void* d_ws, size_t ws_size,
                              hipStream_t stream)
{
    const float* inputs  = (const float*)d_in[0];
    const float* context = (const float*)d_in[1];
    const float* g_in    = (const float*)d_in[2];
    const float* b_in    = (const float*)d_in[3];
    const float* g_ctx   = (const float*)d_in[4];
    const float* b_ctx   = (const float*)d_in[5];
    const float* Wq      = (const float*)d_in[6];
    const float* bq      = (const float*)d_in[7];
    const float* Wk      = (const float*)d_in[8];
    const float* bk      = (const float*)d_in[9];
    const float* Wv      = (const float*)d_in[10];
    const float* bv      = (const float*)d_in[11];
    float* out = (float*)d_out;                      // [8,2048,512] fp32

    const size_t QKV  = 8ull * 2048 * 512;           // 8,388,608
    const size_t WSZ  = 512ull * 512;                // 262,144
    const size_t DOTS = 8ull * 2048 * 2048;          // 33,554,432

    ushort_t* xln   = (ushort_t*)d_ws;
    ushort_t* cln   = xln + QKV;
    ushort_t* WqT   = cln + QKV;
    ushort_t* WkT   = WqT + WSZ;
    ushort_t* WvT   = WkT + WSZ;
    ushort_t* q     = WvT + WSZ;
    ushort_t* kk    = q + QKV;
    ushort_t* v     = kk + QKV;
    ushort_t* vT    = v + QKV;
    ushort_t* edots = vT + QKV;
    float* recip    = (float*)(edots + DOTS);        // 16384
    float* colsum   = recip + 16384;                 // 16384
    float* colrecip = colsum + 16384;                // 16384
    size_t need_bytes = (6 * QKV + 3 * WSZ + DOTS) * 2 + 3 * 16384 * 4;
    if (ws_size < need_bytes) return;  // fail loudly via validation mismatch

    hipMemsetAsync(colsum, 0, 16384 * sizeof(float), stream);

    ln_apply_kernel<<<dim3(16384, 2), 256, 0, stream>>>(
        inputs, context, g_in, b_in, g_ctx, b_ctx, xln, cln);

    wtrans_kernel<<<dim3(16, 16, 3), 256, 0, stream>>>(Wq, Wk, Wv, WqT, WkT, WvT);

    mfma_gemm_kernel<0><<<dim3(4, 128, 1), 256, 0, stream>>>(
        xln, WqT, q, bq, nullptr, nullptr, 512, 512, 0, 0, 0, 0, 1.f);
    mfma_gemm_kernel<0><<<dim3(4, 128, 1), 256, 0, stream>>>(
        cln, WkT, kk, bk, nullptr, nullptr, 512, 512, 0, 0, 0, 0, 1.f);
    mfma_gemm_kernel<0><<<dim3(4, 128, 1), 256, 0, stream>>>(
        cln, WvT, v, bv, nullptr, nullptr, 512, 512, 0, 0, 0, 0, 1.f);

    vtrans_kernel<<<dim3(16, 64, 8), 256, 0, stream>>>(v, vT);

    // edots = exp(scale * q k^T), with column sums accumulated atomically
    mfma_gemm_kernel<1><<<dim3(16, 16, 8), 256, 0, stream>>>(
        q, kk, edots, nullptr, colsum, nullptr, 512, 2048,
        (size_t)2048 * 512, (size_t)2048 * 512, (size_t)2048 * 2048, 0, SCALE_QK);

    colrecip_kernel<<<64, 256, 0, stream>>>(colsum, colrecip);
    rowsum_kernel<<<16384, 256, 0, stream>>>(edots, colrecip, recip);

    // out = diag(recip) * (edots*colrecip) @ v
    mfma_gemm_kernel<2><<<dim3(4, 16, 8), 256, 0, stream>>>(
        edots, vT, out, recip, nullptr, colrecip, 2048, 512,
        (size_t)2048 * 2048, (size_t)512 * 2048, (size_t)2048 * 512, 2048, 1.f);
}

// Round 6
// 317.087 us; speedup vs baseline: 6.6875x; 1.1601x over previous
//
#include <hip/hip_runtime.h>
#include <hip/hip_bf16.h>
#include <math.h>

#define EPSF 1e-8f
#define LN_EPSF 1e-5f
#define SCALE_QK 0.04419417382415922f   // 512^-0.5

typedef unsigned short ushort_t;
typedef __bf16 bhalf;
typedef bhalf bhalf8 __attribute__((ext_vector_type(8)));
typedef float f32x4 __attribute__((ext_vector_type(4)));

__device__ __forceinline__ float b2f(ushort_t u) {
    return __uint_as_float((unsigned)u << 16);
}
// fp32 -> bf16 RNE (matches numpy/jax rounding)
__device__ __forceinline__ ushort_t f2b(float f) {
    unsigned x = __float_as_uint(f);
    return (ushort_t)((x + 0x7fffu + ((x >> 16) & 1u)) >> 16);
}
// async 16B global -> LDS (lands at wave-uniform base + lane*16)
__device__ __forceinline__ void gload16(const ushort_t* g, ushort_t* l) {
    __builtin_amdgcn_global_load_lds(
        (const __attribute__((address_space(1))) unsigned int*)g,
        (__attribute__((address_space(3))) unsigned int*)l, 16, 0, 0);
}

// ---------------------------------------------------------------------------
// LayerNorm: stats + apply + bf16 store in one pass.
// grid (16384, 2), block 256.  Row = 512 floats, 2 per thread.
// ---------------------------------------------------------------------------
__global__ __launch_bounds__(256) void ln_apply_kernel(
    const float* __restrict__ X1, const float* __restrict__ X2,
    const float* __restrict__ g1, const float* __restrict__ b1,
    const float* __restrict__ g2, const float* __restrict__ b2,
    ushort_t* __restrict__ O1, ushort_t* __restrict__ O2)
{
    const bool sec = blockIdx.y != 0;
    const float* X = sec ? X2 : X1;
    const float* g = sec ? g2 : g1;
    const float* b = sec ? b2 : b1;
    ushort_t* O = sec ? O2 : O1;
    const size_t base = (size_t)blockIdx.x * 512;
    const int t = threadIdx.x;
    float a = X[base + t];
    float c = X[base + t + 256];
    float s = a + c;
    float q = fmaf(a, a, c * c);
#pragma unroll
    for (int off = 32; off > 0; off >>= 1) {
        s += __shfl_down(s, off, 64);
        q += __shfl_down(q, off, 64);
    }
    __shared__ float ls[4], lq[4], mv[2];
    int lane = t & 63, w = t >> 6;
    if (lane == 0) { ls[w] = s; lq[w] = q; }
    __syncthreads();
    if (t == 0) {
        float st = ls[0] + ls[1] + ls[2] + ls[3];
        float qt = lq[0] + lq[1] + lq[2] + lq[3];
        float mu = st * (1.0f / 512.0f);
        float var = qt * (1.0f / 512.0f) - mu * mu;
        mv[0] = mu;
        mv[1] = rsqrtf(var + LN_EPSF);
    }
    __syncthreads();
    float mu = mv[0], rstd = mv[1];
    O[base + t]       = f2b((a - mu) * rstd * g[t] + b[t]);
    O[base + t + 256] = f2b((c - mu) * rstd * g[t + 256] + b[t + 256]);
}

// ---------------------------------------------------------------------------
// Transpose 512x512 fp32 weight -> bf16 [n][k].  grid (16,16,3), block 256.
// ---------------------------------------------------------------------------
__global__ __launch_bounds__(256) void wtrans_kernel(
    const float* __restrict__ W0, const float* __restrict__ W1,
    const float* __restrict__ W2,
    ushort_t* __restrict__ T0, ushort_t* __restrict__ T1,
    ushort_t* __restrict__ T2)
{
    const float* W = blockIdx.z == 0 ? W0 : (blockIdx.z == 1 ? W1 : W2);
    ushort_t* T = blockIdx.z == 0 ? T0 : (blockIdx.z == 1 ? T1 : T2);
    __shared__ float tile[32][33];
    int tx = threadIdx.x & 31, ty = threadIdx.x >> 5;
    int r0 = blockIdx.y * 32, c0 = blockIdx.x * 32;
#pragma unroll
    for (int p = 0; p < 4; ++p)
        tile[ty + p * 8][tx] = W[(size_t)(r0 + ty + p * 8) * 512 + c0 + tx];
    __syncthreads();
#pragma unroll
    for (int p = 0; p < 4; ++p)
        T[(size_t)(c0 + ty + p * 8) * 512 + r0 + tx] = f2b(tile[tx][ty + p * 8]);
}

// ---------------------------------------------------------------------------
// Transpose + scale: vT[b,d,j] = v[b,j,d] * colrecip[b,j].  grid (16,64,8).
// ---------------------------------------------------------------------------
__global__ __launch_bounds__(256) void vtrans_scaled_kernel(
    const ushort_t* __restrict__ V, const float* __restrict__ colrecip,
    ushort_t* __restrict__ VT)
{
    __shared__ ushort_t tile[32][33];
    const size_t vb = (size_t)blockIdx.z * 2048 * 512;
    const size_t tb = (size_t)blockIdx.z * 512 * 2048;
    int tx = threadIdx.x & 31, ty = threadIdx.x >> 5;
    int j0 = blockIdx.y * 32, d0 = blockIdx.x * 32;
#pragma unroll
    for (int p = 0; p < 4; ++p)
        tile[ty + p * 8][tx] = V[vb + (size_t)(j0 + ty + p * 8) * 512 + d0 + tx];
    float cr = colrecip[blockIdx.z * 2048 + j0 + tx];
    __syncthreads();
#pragma unroll
    for (int p = 0; p < 4; ++p)
        VT[tb + (size_t)(d0 + ty + p * 8) * 2048 + j0 + tx] =
            f2b(b2f(tile[tx][ty + p * 8]) * cr);
}

// ---------------------------------------------------------------------------
// NT bf16 MFMA GEMM, m97-style: BK=64, unpadded LDS, global_load_lds(16B)
// staging with XOR chunk swizzle (conflict-free ds_read_b128 fragments).
// 128x128 tile, 4 waves, each 64x64 = 4x4 MFMA 16x16x32 tiles.
// MODE 0: +bias (aux[col]),  bf16 store   (q/k/v projections)
// MODE 1: exp(acc*scale),    bf16 store + column sums -> atomic colsum
// MODE 2: *aux[row] (recip), fp32 store   (updates; B pre-scaled by colrecip)
// ---------------------------------------------------------------------------
template <int MODE>
__global__ __launch_bounds__(256) void mfma_gemm_kernel(
    const ushort_t* __restrict__ A, const ushort_t* __restrict__ B,
    void* __restrict__ Cout, const float* __restrict__ aux,
    float* __restrict__ colsum,
    int K, int N, size_t strideA, size_t strideB, size_t strideC,
    int auxStride, float scale)
{
    __shared__ __align__(16) ushort_t As[128 * 64];   // 16 KB
    __shared__ __align__(16) ushort_t Bs[128 * 64];   // 16 KB
    const int tid = threadIdx.x;
    const ushort_t* Ab = A + strideA * blockIdx.z;
    const ushort_t* Bb = B + strideB * blockIdx.z;
    const int m0 = blockIdx.y * 128;
    const int n0 = blockIdx.x * 128;
    const int wave = tid >> 6;
    const int lane = tid & 63;
    const int fm = lane & 15;
    const int fq = lane >> 4;
    const int fm7 = fm & 7;
    const int wm = (wave >> 1) * 64;
    const int wn = (wave & 1) * 64;

    // staging roles: lane covers (row = lrow, 16B chunk = lchunk) of an
    // 8-row group; global chunk is XOR-swizzled by row so that fragment
    // reads are bank-conflict-free.
    const int lrow = lane >> 3;            // 0..7
    const int lchunk = lane & 7;           // 0..7
    const int scs = lchunk ^ lrow;         // swizzled source chunk

    const ushort_t* aSrc[4]; const ushort_t* bSrc[4];
    ushort_t* aDst[4]; ushort_t* bDst[4];
#pragma unroll
    for (int p = 0; p < 4; ++p) {
        int row = wave * 32 + p * 8 + lrow;
        aSrc[p] = Ab + (size_t)(m0 + row) * K + scs * 8;
        bSrc[p] = Bb + (size_t)(n0 + row) * K + scs * 8;
        aDst[p] = As + (wave * 32 + p * 8) * 64 + lane * 8;
        bDst[p] = Bs + (wave * 32 + p * 8) * 64 + lane * 8;
    }

    // fragment read bases (chunk swizzle folded in)
    const int cBase = fq ^ fm7;            // chunk for k-half s=0
    const ushort_t* aFrag[4]; const ushort_t* bFrag[4];
#pragma unroll
    for (int t = 0; t < 4; ++t) {
        aFrag[t] = As + (wm + t * 16 + fm) * 64;
        bFrag[t] = Bs + (wn + t * 16 + fm) * 64;
    }

    f32x4 acc[4][4];
#pragma unroll
    for (int i = 0; i < 4; ++i)
#pragma unroll
        for (int j = 0; j < 4; ++j) acc[i][j] = (f32x4){0.f, 0.f, 0.f, 0.f};

    for (int k0 = 0; k0 < K; k0 += 64) {
        __syncthreads();                    // previous compute done with LDS
#pragma unroll
        for (int p = 0; p < 4; ++p) {
            gload16(aSrc[p] + k0, aDst[p]);
            gload16(bSrc[p] + k0, bDst[p]);
        }
        __syncthreads();                    // drain vmcnt + visibility
#pragma unroll
        for (int s = 0; s < 2; ++s) {
            const int off = ((cBase ^ (s << 2)) << 3);
            bhalf8 af[4], bf[4];
#pragma unroll
            for (int t = 0; t < 4; ++t) {
                af[t] = *(const bhalf8*)(aFrag[t] + off);
                bf[t] = *(const bhalf8*)(bFrag[t] + off);
            }
#pragma unroll
            for (int i = 0; i < 4; ++i)
#pragma unroll
                for (int j = 0; j < 4; ++j)
                    acc[i][j] = __builtin_amdgcn_mfma_f32_16x16x32_bf16(
                        af[i], bf[j], acc[i][j], 0, 0, 0);
        }
    }

    if (MODE == 2) {
        float* C = (float*)Cout + strideC * blockIdx.z;
        const float* rc = aux + (size_t)auxStride * blockIdx.z;
#pragma unroll
        for (int ti = 0; ti < 4; ++ti) {
#pragma unroll
            for (int r = 0; r < 4; ++r) {
                int row = m0 + wm + ti * 16 + fq * 4 + r;
                float rs = rc[row];
#pragma unroll
                for (int tj = 0; tj < 4; ++tj) {
                    int col = n0 + wn + tj * 16 + fm;
                    C[(size_t)row * N + col] = acc[ti][tj][r] * rs;
                }
            }
        }
    } else if (MODE == 1) {
        ushort_t* C = (ushort_t*)Cout + strideC * blockIdx.z;
        float* colpart = (float*)&As[0];
        float psum[4] = {0.f, 0.f, 0.f, 0.f};
#pragma unroll
        for (int ti = 0; ti < 4; ++ti) {
#pragma unroll
            for (int r = 0; r < 4; ++r) {
                int row = m0 + wm + ti * 16 + fq * 4 + r;
#pragma unroll
                for (int tj = 0; tj < 4; ++tj) {
                    int col = n0 + wn + tj * 16 + fm;
                    float e = __expf(acc[ti][tj][r] * scale);
                    ushort_t h = f2b(e);
                    C[(size_t)row * N + col] = h;
                    psum[tj] += b2f(h);   // sum the quantized values
                }
            }
        }
        // reduce over fq (lanes 16/32 apart hold same column)
#pragma unroll
        for (int tj = 0; tj < 4; ++tj) {
            psum[tj] += __shfl_xor(psum[tj], 16, 64);
            psum[tj] += __shfl_xor(psum[tj], 32, 64);
        }
        __syncthreads();                    // done reading As as fragments
        if (tid < 128) colpart[tid] = 0.f;
        __syncthreads();
        if (fq == 0) {
#pragma unroll
            for (int tj = 0; tj < 4; ++tj)
                atomicAdd(&colpart[wn + tj * 16 + fm], psum[tj]);
        }
        __syncthreads();
        if (tid < 128)
            atomicAdd(&colsum[2048 * blockIdx.z + n0 + tid], colpart[tid]);
    } else {
        ushort_t* C = (ushort_t*)Cout + strideC * blockIdx.z;
#pragma unroll
        for (int ti = 0; ti < 4; ++ti) {
#pragma unroll
            for (int r = 0; r < 4; ++r) {
                int row = m0 + wm + ti * 16 + fq * 4 + r;
#pragma unroll
                for (int tj = 0; tj < 4; ++tj) {
                    int col = n0 + wn + tj * 16 + fm;
                    C[(size_t)row * N + col] = f2b(acc[ti][tj][r] + aux[col]);
                }
            }
        }
    }
}

// ---------------------------------------------------------------------------
// colrecip[t] = 1/colsum[t].  16384 elems, grid 64, block 256.
// ---------------------------------------------------------------------------
__global__ __launch_bounds__(256) void colrecip_kernel(
    const float* __restrict__ cs, float* __restrict__ cr)
{
    int t = blockIdx.x * 256 + threadIdx.x;
    cr[t] = 1.0f / cs[t];
}

// ---------------------------------------------------------------------------
// recip[i] = 1/(sum_j edots[i,j]*colrecip[j] + 2049*EPS).  grid 16384.
// ---------------------------------------------------------------------------
__global__ __launch_bounds__(256) void rowsum_kernel(
    const ushort_t* __restrict__ E, const float* __restrict__ colrecip,
    float* __restrict__ recip)
{
    const uint4* rp = (const uint4*)(E + (size_t)blockIdx.x * 2048);
    const float4* cr = (const float4*)(colrecip + (blockIdx.x >> 11) * 2048);
    uint4 u = rp[threadIdx.x];
    float4 c0 = cr[threadIdx.x * 2];
    float4 c1 = cr[threadIdx.x * 2 + 1];
    float s = b2f((ushort_t)(u.x & 0xffffu)) * c0.x
            + b2f((ushort_t)(u.x >> 16))    * c0.y
            + b2f((ushort_t)(u.y & 0xffffu)) * c0.z
            + b2f((ushort_t)(u.y >> 16))    * c0.w
            + b2f((ushort_t)(u.z & 0xffffu)) * c1.x
            + b2f((ushort_t)(u.z >> 16))    * c1.y
            + b2f((ushort_t)(u.w & 0xffffu)) * c1.z
            + b2f((ushort_t)(u.w >> 16))    * c1.w;
#pragma unroll
    for (int off = 32; off > 0; off >>= 1) s += __shfl_down(s, off, 64);
    __shared__ float ls[4];
    int lane = threadIdx.x & 63, wv = threadIdx.x >> 6;
    if (lane == 0) ls[wv] = s;
    __syncthreads();
    if (threadIdx.x == 0)
        recip[blockIdx.x] = 1.0f / (ls[0] + ls[1] + ls[2] + ls[3] + 2.049e-5f);
}

// ---------------------------------------------------------------------------
extern "C" void kernel_launch(void* const* d_in, const int* in_sizes, int n_in,
                              void* d_out, int out_size, void* d_ws, size_t ws_size,
                              hipStream_t stream)
{
    const float* inputs  = (const float*)d_in[0];
    const float* context = (const float*)d_in[1];
    const float* g_in    = (const float*)d_in[2];
    const float* b_in    = (const float*)d_in[3];
    const float* g_ctx   = (const float*)d_in[4];
    const float* b_ctx   = (const float*)d_in[5];
    const float* Wq      = (const float*)d_in[6];
    const float* bq      = (const float*)d_in[7];
    const float* Wk      = (const float*)d_in[8];
    const float* bk      = (const float*)d_in[9];
    const float* Wv      = (const float*)d_in[10];
    const float* bv      = (const float*)d_in[11];
    float* out = (float*)d_out;                      // [8,2048,512] fp32

    const size_t QKV  = 8ull * 2048 * 512;           // 8,388,608
    const size_t WSZ  = 512ull * 512;                // 262,144
    const size_t DOTS = 8ull * 2048 * 2048;          // 33,554,432

    ushort_t* xln   = (ushort_t*)d_ws;
    ushort_t* cln   = xln + QKV;
    ushort_t* WqT   = cln + QKV;
    ushort_t* WkT   = WqT + WSZ;
    ushort_t* WvT   = WkT + WSZ;
    ushort_t* q     = WvT + WSZ;
    ushort_t* kk    = q + QKV;
    ushort_t* v     = kk + QKV;
    ushort_t* vTs   = v + QKV;                       // v^T pre-scaled by colrecip
    ushort_t* edots = vTs + QKV;
    float* recip    = (float*)(edots + DOTS);        // 16384
    float* colsum   = recip + 16384;                 // 16384
    float* colrecip = colsum + 16384;                // 16384
    size_t need_bytes = (6 * QKV + 3 * WSZ + DOTS) * 2 + 3 * 16384 * 4;
    if (ws_size < need_bytes) return;  // fail loudly via validation mismatch

    hipMemsetAsync(colsum, 0, 16384 * sizeof(float), stream);

    ln_apply_kernel<<<dim3(16384, 2), 256, 0, stream>>>(
        inputs, context, g_in, b_in, g_ctx, b_ctx, xln, cln);

    wtrans_kernel<<<dim3(16, 16, 3), 256, 0, stream>>>(Wq, Wk, Wv, WqT, WkT, WvT);

    mfma_gemm_kernel<0><<<dim3(4, 128, 1), 256, 0, stream>>>(
        xln, WqT, q, bq, nullptr, 512, 512, 0, 0, 0, 0, 1.f);
    mfma_gemm_kernel<0><<<dim3(4, 128, 1), 256, 0, stream>>>(
        cln, WkT, kk, bk, nullptr, 512, 512, 0, 0, 0, 0, 1.f);
    mfma_gemm_kernel<0><<<dim3(4, 128, 1), 256, 0, stream>>>(
        cln, WvT, v, bv, nullptr, 512, 512, 0, 0, 0, 0, 1.f);

    // edots = exp(scale * q k^T), with column sums accumulated atomically
    mfma_gemm_kernel<1><<<dim3(16, 16, 8), 256, 0, stream>>>(
        q, kk, edots, nullptr, colsum, 512, 2048,
        (size_t)2048 * 512, (size_t)2048 * 512, (size_t)2048 * 2048, 0, SCALE_QK);

    colrecip_kernel<<<64, 256, 0, stream>>>(colsum, colrecip);

    // vTs[b,d,j] = v[b,j,d] * colrecip[b,j]
    vtrans_scaled_kernel<<<dim3(16, 64, 8), 256, 0, stream>>>(v, colrecip, vTs);

    rowsum_kernel<<<16384, 256, 0, stream>>>(edots, colrecip, recip);

    // out = diag(recip) * edots @ vTs^T
    mfma_gemm_kernel<2><<<dim3(4, 16, 8), 256, 0, stream>>>(
        edots, vTs, out, recip, nullptr, 2048, 512,
        (size_t)2048 * 2048, (size_t)512 * 2048, (size_t)2048 * 512, 2048, 1.f);
}

// Round 7
// 308.436 us; speedup vs baseline: 6.8751x; 1.0280x over previous
//
#include <hip/hip_runtime.h>
#include <hip/hip_bf16.h>
#include <math.h>

#define EPSF 1e-8f
#define LN_EPSF 1e-5f
#define SCALE_QK 0.04419417382415922f   // 512^-0.5

typedef unsigned short ushort_t;
typedef __bf16 bhalf;
typedef bhalf bhalf8 __attribute__((ext_vector_type(8)));
typedef float f32x4 __attribute__((ext_vector_type(4)));

__device__ __forceinline__ float b2f(ushort_t u) {
    return __uint_as_float((unsigned)u << 16);
}
// fp32 -> bf16 RNE (matches numpy/jax rounding)
__device__ __forceinline__ ushort_t f2b(float f) {
    unsigned x = __float_as_uint(f);
    return (ushort_t)((x + 0x7fffu + ((x >> 16) & 1u)) >> 16);
}
// async 16B global -> LDS (lands at wave-uniform base + lane*16)
__device__ __forceinline__ void gload16(const ushort_t* g, ushort_t* l) {
    __builtin_amdgcn_global_load_lds(
        (const __attribute__((address_space(1))) unsigned int*)g,
        (__attribute__((address_space(3))) unsigned int*)l, 16, 0, 0);
}

// ---------------------------------------------------------------------------
// Bias helper vectors: wqbk = Wq@bk, wkbq = Wk@bq, cc = bq.bk.
// grid (32,3), block 256.  (All zero for this problem's inputs, but exact.)
// ---------------------------------------------------------------------------
__global__ __launch_bounds__(256) void mv_bias_kernel(
    const float* __restrict__ Wq, const float* __restrict__ Wk,
    const float* __restrict__ bq, const float* __restrict__ bk,
    float* __restrict__ wqbk, float* __restrict__ wkbq, float* __restrict__ cc)
{
    __shared__ float ls[4];
    const int y = blockIdx.y;
    const int t = threadIdx.x;
    if (y == 2) {
        if (blockIdx.x != 0) return;
        float s = bq[t] * bk[t] + bq[t + 256] * bk[t + 256];
#pragma unroll
        for (int off = 32; off > 0; off >>= 1) s += __shfl_down(s, off, 64);
        int lane = t & 63, w = t >> 6;
        if (lane == 0) ls[w] = s;
        __syncthreads();
        if (t == 0) cc[0] = ls[0] + ls[1] + ls[2] + ls[3];
        return;
    }
    const float* W = y ? Wk : Wq;
    const float* v = y ? bq : bk;
    float* o = y ? wkbq : wqbk;
    const int row = blockIdx.x * 16 + (t >> 4);
    const int l = t & 15;
    const float* wr = W + (size_t)row * 512 + l * 32;
    const float* vr = v + l * 32;
    float s = 0.f;
#pragma unroll
    for (int c = 0; c < 32; ++c) s += wr[c] * vr[c];
#pragma unroll
    for (int off = 8; off > 0; off >>= 1) s += __shfl_down(s, off, 16);
    if (l == 0) o[row] = s;
}

// ---------------------------------------------------------------------------
// LayerNorm: stats + apply + bf16 store + dot with bias helper (t1/t2).
// grid (16384, 2), block 256.  Row = 512 floats, float2 per thread.
// ---------------------------------------------------------------------------
__global__ __launch_bounds__(256) void ln_apply_kernel(
    const float* __restrict__ X1, const float* __restrict__ X2,
    const float* __restrict__ g1, const float* __restrict__ b1,
    const float* __restrict__ g2, const float* __restrict__ b2,
    const float* __restrict__ wb1, const float* __restrict__ wb2,
    ushort_t* __restrict__ O1, ushort_t* __restrict__ O2,
    float* __restrict__ T1, float* __restrict__ T2)
{
    const bool sec = blockIdx.y != 0;
    const float* X = sec ? X2 : X1;
    const float* g = sec ? g2 : g1;
    const float* b = sec ? b2 : b1;
    const float* wb = sec ? wb2 : wb1;
    ushort_t* O = sec ? O2 : O1;
    float* T = sec ? T2 : T1;
    const size_t base = (size_t)blockIdx.x * 512;
    const int t = threadIdx.x;
    float2 x = ((const float2*)(X + base))[t];
    float s = x.x + x.y;
    float q = fmaf(x.x, x.x, x.y * x.y);
#pragma unroll
    for (int off = 32; off > 0; off >>= 1) {
        s += __shfl_down(s, off, 64);
        q += __shfl_down(q, off, 64);
    }
    __shared__ float ls[4], lq[4], mv[2], ld[4];
    int lane = t & 63, w = t >> 6;
    if (lane == 0) { ls[w] = s; lq[w] = q; }
    __syncthreads();
    if (t == 0) {
        float st = ls[0] + ls[1] + ls[2] + ls[3];
        float qt = lq[0] + lq[1] + lq[2] + lq[3];
        float mu = st * (1.0f / 512.0f);
        float var = qt * (1.0f / 512.0f) - mu * mu;
        mv[0] = mu;
        mv[1] = rsqrtf(var + LN_EPSF);
    }
    __syncthreads();
    const float mu = mv[0], rstd = mv[1];
    float2 gg = ((const float2*)g)[t];
    float2 bb = ((const float2*)b)[t];
    float2 ww = ((const float2*)wb)[t];
    float o0 = (x.x - mu) * rstd * gg.x + bb.x;
    float o1 = (x.y - mu) * rstd * gg.y + bb.y;
    ((unsigned*)O)[blockIdx.x * 256 + t] =
        (unsigned)f2b(o0) | ((unsigned)f2b(o1) << 16);
    float d = o0 * ww.x + o1 * ww.y;
#pragma unroll
    for (int off = 32; off > 0; off >>= 1) d += __shfl_down(d, off, 64);
    if (lane == 0) ld[w] = d;
    __syncthreads();
    if (t == 0) T[blockIdx.x] = ld[0] + ld[1] + ld[2] + ld[3];
}

// ---------------------------------------------------------------------------
// Weight prep: z=0,1 cast Wq,Wk -> bf16 (same layout); z=2 transpose Wv.
// grid (16,16,3), block 256.
// ---------------------------------------------------------------------------
__global__ __launch_bounds__(256) void wprep_kernel(
    const float* __restrict__ Wq, const float* __restrict__ Wk,
    const float* __restrict__ Wv,
    ushort_t* __restrict__ Wqb, ushort_t* __restrict__ Wkb,
    ushort_t* __restrict__ WvT)
{
    const int z = blockIdx.z;
    if (z < 2) {
        const float* W = z ? Wk : Wq;
        ushort_t* T = z ? Wkb : Wqb;
        size_t idx = ((size_t)(blockIdx.y * 16 + blockIdx.x)) * 1024 + threadIdx.x * 4;
        float4 f = *(const float4*)(W + idx);
        uint2 u;
        u.x = (unsigned)f2b(f.x) | ((unsigned)f2b(f.y) << 16);
        u.y = (unsigned)f2b(f.z) | ((unsigned)f2b(f.w) << 16);
        *(uint2*)(T + idx) = u;
        return;
    }
    __shared__ float tile[32][33];
    int tx = threadIdx.x & 31, ty = threadIdx.x >> 5;
    int r0 = blockIdx.y * 32, c0 = blockIdx.x * 32;
#pragma unroll
    for (int p = 0; p < 4; ++p)
        tile[ty + p * 8][tx] = Wv[(size_t)(r0 + ty + p * 8) * 512 + c0 + tx];
    __syncthreads();
#pragma unroll
    for (int p = 0; p < 4; ++p)
        WvT[(size_t)(c0 + ty + p * 8) * 512 + r0 + tx] = f2b(tile[tx][ty + p * 8]);
}

// ---------------------------------------------------------------------------
// colrecip[t] = 1/colsum[t] (+bf16 copy).  16384 elems, grid 64, block 256.
// ---------------------------------------------------------------------------
__global__ __launch_bounds__(256) void colrecip_kernel(
    const float* __restrict__ cs, float* __restrict__ cr,
    ushort_t* __restrict__ crs)
{
    int t = blockIdx.x * 256 + threadIdx.x;
    float r = 1.0f / cs[t];
    cr[t] = r;
    crs[t] = f2b(r);
}

// ---------------------------------------------------------------------------
// NT bf16 MFMA GEMM: C[m,n] = sum_k A[m,k]*B[n,k], k-major bf16, m97-style
// staging (BK=64, global_load_lds 16B, XOR chunk swizzle, conflict-free).
// 128x128 tile, 4 waves, 4x4 MFMA 16x16x32 each.
// MODE 0: plain bf16 store                         (M = Wq Wk^T;  KM = cln M^T)
// MODE 1: exp(scale*(acc+t1[row]+t2[col]+cc)) bf16 + atomic colsum  (edots)
// MODE 2: fp32 store * 1/(rowsum+eps); rowsum via MFMA side-column with
//         B-frag = bf16 colrecip staged in LDS                       (out)
// MODE 3: (acc + bias[row]) * crcol[col], bf16 store                 (vTs)
// ---------------------------------------------------------------------------
template <int MODE>
__global__ __launch_bounds__(256) void mfma_gemm_kernel(
    const ushort_t* __restrict__ A, const ushort_t* __restrict__ B,
    void* __restrict__ Cout,
    const float* __restrict__ bias,     // MODE3: row bias (bv)
    const float* __restrict__ t1,       // MODE1: row term
    const float* __restrict__ t2,       // MODE1: col term
    const float* __restrict__ cc,       // MODE1: scalar term
    float* __restrict__ colsum,         // MODE1
    const float* __restrict__ crcol,    // MODE3: f32 colrecip
    const ushort_t* __restrict__ crs,   // MODE2: bf16 colrecip
    int K, int N, size_t strideA, size_t strideB, size_t strideC,
    float scale)
{
    __shared__ __align__(16) ushort_t As[128 * 64];   // 16 KB
    __shared__ __align__(16) ushort_t Bs[128 * 64];   // 16 KB
    __shared__ __align__(16) ushort_t crs_lds[(MODE == 2) ? 2048 : 8];
    const int tid = threadIdx.x;
    const ushort_t* Ab = A + strideA * blockIdx.z;
    const ushort_t* Bb = B + strideB * blockIdx.z;
    const int m0 = blockIdx.y * 128;
    const int n0 = blockIdx.x * 128;
    const int wave = tid >> 6;
    const int lane = tid & 63;
    const int fm = lane & 15;
    const int fq = lane >> 4;
    const int fm7 = fm & 7;
    const int wm = (wave >> 1) * 64;
    const int wn = (wave & 1) * 64;

    const int lrow = lane >> 3;            // 0..7
    const int lchunk = lane & 7;           // 0..7
    const int scs = lchunk ^ lrow;         // swizzled source chunk

    const ushort_t* aSrc[4]; const ushort_t* bSrc[4];
    ushort_t* aDst[4]; ushort_t* bDst[4];
#pragma unroll
    for (int p = 0; p < 4; ++p) {
        int row = wave * 32 + p * 8 + lrow;
        aSrc[p] = Ab + (size_t)(m0 + row) * K + scs * 8;
        bSrc[p] = Bb + (size_t)(n0 + row) * K + scs * 8;
        aDst[p] = As + (wave * 32 + p * 8) * 64 + lane * 8;
        bDst[p] = Bs + (wave * 32 + p * 8) * 64 + lane * 8;
    }

    if (MODE == 2) {
        uint4 c4 = *(const uint4*)(crs + (size_t)blockIdx.z * 2048 + tid * 8);
        *(uint4*)&crs_lds[tid * 8] = c4;
    }

    const int cBase = fq ^ fm7;
    const ushort_t* aFrag[4]; const ushort_t* bFrag[4];
#pragma unroll
    for (int t = 0; t < 4; ++t) {
        aFrag[t] = As + (wm + t * 16 + fm) * 64;
        bFrag[t] = Bs + (wn + t * 16 + fm) * 64;
    }

    f32x4 acc[4][4];
    f32x4 sacc[4];
#pragma unroll
    for (int i = 0; i < 4; ++i) {
        sacc[i] = (f32x4){0.f, 0.f, 0.f, 0.f};
#pragma unroll
        for (int j = 0; j < 4; ++j) acc[i][j] = (f32x4){0.f, 0.f, 0.f, 0.f};
    }

    for (int k0 = 0; k0 < K; k0 += 64) {
        __syncthreads();
#pragma unroll
        for (int p = 0; p < 4; ++p) {
            gload16(aSrc[p] + k0, aDst[p]);
            gload16(bSrc[p] + k0, bDst[p]);
        }
        __syncthreads();
#pragma unroll
        for (int s = 0; s < 2; ++s) {
            const int off = ((cBase ^ (s << 2)) << 3);
            bhalf8 af[4], bf[4];
#pragma unroll
            for (int t = 0; t < 4; ++t) {
                af[t] = *(const bhalf8*)(aFrag[t] + off);
                bf[t] = *(const bhalf8*)(bFrag[t] + off);
            }
#pragma unroll
            for (int i = 0; i < 4; ++i)
#pragma unroll
                for (int j = 0; j < 4; ++j)
                    acc[i][j] = __builtin_amdgcn_mfma_f32_16x16x32_bf16(
                        af[i], bf[j], acc[i][j], 0, 0, 0);
            if (MODE == 2) {
                bhalf8 bc = *(const bhalf8*)&crs_lds[k0 + (s << 5) + (fq << 3)];
#pragma unroll
                for (int i = 0; i < 4; ++i)
                    sacc[i] = __builtin_amdgcn_mfma_f32_16x16x32_bf16(
                        af[i], bc, sacc[i], 0, 0, 0);
            }
        }
    }

    if (MODE == 2) {
        float* C = (float*)Cout + strideC * blockIdx.z;
#pragma unroll
        for (int ti = 0; ti < 4; ++ti) {
#pragma unroll
            for (int r = 0; r < 4; ++r) {
                int row = m0 + wm + ti * 16 + fq * 4 + r;
                float rs = 1.0f / (sacc[ti][r] + 2.049e-5f);
#pragma unroll
                for (int tj = 0; tj < 4; ++tj) {
                    int col = n0 + wn + tj * 16 + fm;
                    C[(size_t)row * N + col] = acc[ti][tj][r] * rs;
                }
            }
        }
    } else if (MODE == 1) {
        ushort_t* C = (ushort_t*)Cout + strideC * blockIdx.z;
        const float cv = cc[0];
        float t2v[4];
#pragma unroll
        for (int tj = 0; tj < 4; ++tj)
            t2v[tj] = t2[(size_t)blockIdx.z * 2048 + n0 + wn + tj * 16 + fm];
        float* colpart = (float*)&As[0];
        float psum[4] = {0.f, 0.f, 0.f, 0.f};
#pragma unroll
        for (int ti = 0; ti < 4; ++ti) {
#pragma unroll
            for (int r = 0; r < 4; ++r) {
                int row = m0 + wm + ti * 16 + fq * 4 + r;
                float t1v = t1[(size_t)blockIdx.z * 2048 + row];
#pragma unroll
                for (int tj = 0; tj < 4; ++tj) {
                    int col = n0 + wn + tj * 16 + fm;
                    float e = __expf((acc[ti][tj][r] + t1v + t2v[tj] + cv) * scale);
                    ushort_t h = f2b(e);
                    C[(size_t)row * N + col] = h;
                    psum[tj] += b2f(h);   // sum the quantized values
                }
            }
        }
#pragma unroll
        for (int tj = 0; tj < 4; ++tj) {
            psum[tj] += __shfl_xor(psum[tj], 16, 64);
            psum[tj] += __shfl_xor(psum[tj], 32, 64);
        }
        __syncthreads();
        if (tid < 128) colpart[tid] = 0.f;
        __syncthreads();
        if (fq == 0) {
#pragma unroll
            for (int tj = 0; tj < 4; ++tj)
                atomicAdd(&colpart[wn + tj * 16 + fm], psum[tj]);
        }
        __syncthreads();
        if (tid < 128)
            atomicAdd(&colsum[(size_t)blockIdx.z * 2048 + n0 + tid], colpart[tid]);
    } else if (MODE == 3) {
        ushort_t* C = (ushort_t*)Cout + strideC * blockIdx.z;
        float crv[4];
#pragma unroll
        for (int tj = 0; tj < 4; ++tj)
            crv[tj] = crcol[(size_t)blockIdx.z * 2048 + n0 + wn + tj * 16 + fm];
#pragma unroll
        for (int ti = 0; ti < 4; ++ti) {
#pragma unroll
            for (int r = 0; r < 4; ++r) {
                int row = m0 + wm + ti * 16 + fq * 4 + r;
                float bvv = bias[row];
#pragma unroll
                for (int tj = 0; tj < 4; ++tj) {
                    int col = n0 + wn + tj * 16 + fm;
                    C[(size_t)row * N + col] = f2b((acc[ti][tj][r] + bvv) * crv[tj]);
                }
            }
        }
    } else {
        ushort_t* C = (ushort_t*)Cout + strideC * blockIdx.z;
#pragma unroll
        for (int ti = 0; ti < 4; ++ti) {
#pragma unroll
            for (int r = 0; r < 4; ++r) {
                int row = m0 + wm + ti * 16 + fq * 4 + r;
#pragma unroll
                for (int tj = 0; tj < 4; ++tj) {
                    int col = n0 + wn + tj * 16 + fm;
                    C[(size_t)row * N + col] = f2b(acc[ti][tj][r]);
                }
            }
        }
    }
}

// ---------------------------------------------------------------------------
extern "C" void kernel_launch(void* const* d_in, const int* in_sizes, int n_in,
                              void* d_out, int out_size, void* d_ws, size_t ws_size,
                              hipStream_t stream)
{
    const float* inputs  = (const float*)d_in[0];
    const float* context = (const float*)d_in[1];
    const float* g_in    = (const float*)d_in[2];
    const float* b_in    = (const float*)d_in[3];
    const float* g_ctx   = (const float*)d_in[4];
    const float* b_ctx   = (const float*)d_in[5];
    const float* Wq      = (const float*)d_in[6];
    const float* bq      = (const float*)d_in[7];
    const float* Wk      = (const float*)d_in[8];
    const float* bk      = (const float*)d_in[9];
    const float* Wv      = (const float*)d_in[10];
    const float* bv      = (const float*)d_in[11];
    float* out = (float*)d_out;                      // [8,2048,512] fp32

    const size_t QKV  = 8ull * 2048 * 512;           // 8,388,608
    const size_t WSZ  = 512ull * 512;                // 262,144
    const size_t DOTS = 8ull * 2048 * 2048;          // 33,554,432

    ushort_t* xln   = (ushort_t*)d_ws;
    ushort_t* cln   = xln + QKV;
    ushort_t* Wqb   = cln + QKV;
    ushort_t* Wkb   = Wqb + WSZ;
    ushort_t* WvT   = Wkb + WSZ;
    ushort_t* Mb    = WvT + WSZ;                     // Wq Wk^T, bf16 [512][512]
    ushort_t* KM    = Mb + WSZ;                      // cln M^T [16384][512]
    ushort_t* vTs   = KM + QKV;                      // (cln Wv + bv)^T * cr
    ushort_t* edots = vTs + QKV;
    ushort_t* crs   = edots + DOTS;                  // bf16 colrecip [16384]
    float* fbase    = (float*)(crs + 16384);
    float* colsum   = fbase;                         // 16384
    float* colrecip = colsum + 16384;                // 16384
    float* t1       = colrecip + 16384;              // 16384
    float* t2       = t1 + 16384;                    // 16384
    float* wqbk     = t2 + 16384;                    // 512
    float* wkbq     = wqbk + 512;                    // 512
    float* cc       = wkbq + 512;                    // 1
    size_t need_bytes = (4 * QKV + 4 * WSZ + DOTS + 16384) * 2
                      + (4 * 16384 + 1024 + 1) * 4;
    if (ws_size < need_bytes) return;  // fail loudly via validation mismatch

    hipMemsetAsync(colsum, 0, 16384 * sizeof(float), stream);

    mv_bias_kernel<<<dim3(32, 3), 256, 0, stream>>>(Wq, Wk, bq, bk, wqbk, wkbq, cc);

    ln_apply_kernel<<<dim3(16384, 2), 256, 0, stream>>>(
        inputs, context, g_in, b_in, g_ctx, b_ctx, wqbk, wkbq, xln, cln, t1, t2);

    wprep_kernel<<<dim3(16, 16, 3), 256, 0, stream>>>(Wq, Wk, Wv, Wqb, Wkb, WvT);

    // M = Wq @ Wk^T   [512,512]
    mfma_gemm_kernel<0><<<dim3(4, 4, 1), 256, 0, stream>>>(
        Wqb, Wkb, Mb, nullptr, nullptr, nullptr, nullptr, nullptr, nullptr, nullptr,
        512, 512, 0, 0, 0, 1.f);

    // KM[j][a] = sum_b cln[j,b] M[a,b]   [16384,512]
    mfma_gemm_kernel<0><<<dim3(4, 128, 1), 256, 0, stream>>>(
        cln, Mb, KM, nullptr, nullptr, nullptr, nullptr, nullptr, nullptr, nullptr,
        512, 512, 0, 0, 0, 1.f);

    // edots = exp(scale*(xln KM^T + t1 + t2 + cc)), column sums -> colsum
    mfma_gemm_kernel<1><<<dim3(16, 16, 8), 256, 0, stream>>>(
        xln, KM, edots, nullptr, t1, t2, cc, colsum, nullptr, nullptr,
        512, 2048, (size_t)2048 * 512, (size_t)2048 * 512, (size_t)2048 * 2048,
        SCALE_QK);

    colrecip_kernel<<<64, 256, 0, stream>>>(colsum, colrecip, crs);

    // vTs[b,d,j] = (sum_b' WvT[d,b'] cln[j,b'] + bv[d]) * colrecip[b,j]
    mfma_gemm_kernel<3><<<dim3(16, 4, 8), 256, 0, stream>>>(
        WvT, cln, vTs, bv, nullptr, nullptr, nullptr, nullptr, colrecip, nullptr,
        512, 2048, 0, (size_t)2048 * 512, (size_t)512 * 2048, 1.f);

    // out = diag(1/(E cr + eps)) * E @ vTs^T   (rowsum via MFMA side-column)
    mfma_gemm_kernel<2><<<dim3(4, 16, 8), 256, 0, stream>>>(
        edots, vTs, out, nullptr, nullptr, nullptr, nullptr, nullptr, nullptr, crs,
        2048, 512, (size_t)2048 * 2048, (size_t)512 * 2048, (size_t)2048 * 512,
        1.f);
}